// Round 2
// baseline (1508.378 us; speedup 1.0000x reference)
//
#include <hip/hip_runtime.h>
#include <math.h>

#define BB 128
#define TT 2048
#define DD 512
#define TD2 1024   // 2*D
#define NEG_INF_F (-1e9f)
#define TCHUNK 128
#define NCHUNK (TT / TCHUNK)   // 16

// ---------------------------------------------------------------------------
// K1: attention logits ca[b,t] = sum_d past[b,t,d] * (control[b,d]*W_ca[d]) + b_ca
// grid: (NCHUNK, B), block: 256 (4 waves, 1 wave per row, 32 rows/wave)
// Streams past_controls half: 512 MiB. Expect HBM-bound.
// ---------------------------------------------------------------------------
__global__ __launch_bounds__(256) void ca_kernel(
    const float* __restrict__ past, const float* __restrict__ control,
    const float* __restrict__ W_ca, const float* __restrict__ b_ca,
    float* __restrict__ ca) {
  const int b = blockIdx.y;
  const int chunk = blockIdx.x;
  const int lane = threadIdx.x & 63;
  const int wave = threadIdx.x >> 6;
  const int d0 = lane * 8;

  const float4* ctrl4 = (const float4*)(control + (size_t)b * DD);
  const float4* wca4  = (const float4*)(W_ca);
  float4 c0 = ctrl4[lane * 2], c1 = ctrl4[lane * 2 + 1];
  float4 w0 = wca4[lane * 2],  w1 = wca4[lane * 2 + 1];
  float v0 = c0.x * w0.x, v1 = c0.y * w0.y, v2 = c0.z * w0.z, v3 = c0.w * w0.w;
  float v4 = c1.x * w1.x, v5 = c1.y * w1.y, v6 = c1.z * w1.z, v7 = c1.w * w1.w;
  const float bca = b_ca[0];

  const int tbase = chunk * TCHUNK;
  #pragma unroll 2
  for (int i = 0; i < TCHUNK / 4; ++i) {
    const int t = tbase + wave + i * 4;
    const float4* row = (const float4*)(past + ((size_t)b * TT + t) * TD2 + d0);
    float4 p0 = row[0], p1 = row[1];
    float s = p0.x * v0 + p0.y * v1 + p0.z * v2 + p0.w * v3
            + p1.x * v4 + p1.y * v5 + p1.z * v6 + p1.w * v7;
    #pragma unroll
    for (int off = 32; off > 0; off >>= 1) s += __shfl_xor(s, off, 64);
    if (lane == 0) ca[(size_t)b * TT + t] = s + bca;
  }
}

// ---------------------------------------------------------------------------
// K2: per-b masked softmax over ca[b,:] (in place -> normalized weights),
//     plus sigmoid gate[b] = sigmoid(control[b,:] @ W_m3 + b_m3)
// grid: B, block: 256
// ---------------------------------------------------------------------------
__global__ __launch_bounds__(256) void softmax_gate_kernel(
    float* __restrict__ ca, const float* __restrict__ control,
    const float* __restrict__ W_m3, const float* __restrict__ b_m3,
    float* __restrict__ gate) {
  const int b = blockIdx.x;
  const int tid = threadIdx.x;
  const int lane = tid & 63, wave = tid >> 6;
  __shared__ float red[4], red2[4], red3[4];

  float v[8];
  float mx = -INFINITY;
  #pragma unroll
  for (int i = 0; i < 8; ++i) {
    float x = ca[(size_t)b * TT + tid + i * 256];
    if (x == 0.0f) x = NEG_INF_F;   // mask: exact-zero logits get -1e9
    v[i] = x;
    mx = fmaxf(mx, x);
  }
  #pragma unroll
  for (int off = 32; off > 0; off >>= 1) mx = fmaxf(mx, __shfl_xor(mx, off, 64));
  if (lane == 0) red[wave] = mx;
  __syncthreads();
  mx = fmaxf(fmaxf(red[0], red[1]), fmaxf(red[2], red[3]));

  float sum = 0.0f;
  #pragma unroll
  for (int i = 0; i < 8; ++i) { v[i] = expf(v[i] - mx); sum += v[i]; }
  #pragma unroll
  for (int off = 32; off > 0; off >>= 1) sum += __shfl_xor(sum, off, 64);
  if (lane == 0) red2[wave] = sum;
  __syncthreads();
  sum = red2[0] + red2[1] + red2[2] + red2[3];
  const float inv = 1.0f / sum;
  #pragma unroll
  for (int i = 0; i < 8; ++i) ca[(size_t)b * TT + tid + i * 256] = v[i] * inv;

  // gate
  float g = control[(size_t)b * DD + tid] * W_m3[tid]
          + control[(size_t)b * DD + tid + 256] * W_m3[tid + 256];
  #pragma unroll
  for (int off = 32; off > 0; off >>= 1) g += __shfl_xor(g, off, 64);
  if (lane == 0) red3[wave] = g;
  __syncthreads();
  if (tid == 0) {
    float s = red3[0] + red3[1] + red3[2] + red3[3] + b_m3[0];
    gate[b] = 1.0f / (1.0f + expf(-s));
  }
}

// ---------------------------------------------------------------------------
// K3: partial weighted sums of past_memories (second half of each row).
// grid: (NCHUNK, B), block: 256. Each thread owns 2 d's (float2 = 2KB/row
// coalesced). Deterministic partials to workspace (no atomics).
// ---------------------------------------------------------------------------
__global__ __launch_bounds__(256) void msa_partial_kernel(
    const float* __restrict__ past, const float* __restrict__ w,
    float* __restrict__ partials) {
  const int b = blockIdx.y, chunk = blockIdx.x;
  const int tid = threadIdx.x;
  const int d = tid * 2;
  const int tbase = chunk * TCHUNK;
  const float* base = past + ((size_t)b * TT + tbase) * TD2 + DD + d;
  const float* wbase = w + (size_t)b * TT + tbase;
  float ax = 0.0f, ay = 0.0f;
  #pragma unroll 4
  for (int r = 0; r < TCHUNK; ++r) {
    const float wt = wbase[r];
    const float2 p = *(const float2*)(base + (size_t)r * TD2);
    ax += wt * p.x; ay += wt * p.y;
  }
  float2* out = (float2*)(partials + ((size_t)(b * NCHUNK + chunk)) * DD + d);
  *out = make_float2(ax, ay);
}

// ---------------------------------------------------------------------------
// K5: m1[b,j] = concat(memory,read)[b,:] @ W_m1[:,j] + b_m1[j]
// grid: (2, B) — one j-half (256 cols) per block. block 256, 1 output/thread.
// W_m1 is L2-resident after first touch per XCD.
// ---------------------------------------------------------------------------
__global__ __launch_bounds__(256) void m1_kernel(
    const float* __restrict__ memory, const float* __restrict__ read,
    const float* __restrict__ W_m1, const float* __restrict__ b_m1,
    float* __restrict__ m1) {
  const int half = blockIdx.x, b = blockIdx.y, tid = threadIdx.x;
  __shared__ float x[TD2];
  if (tid < 128) ((float4*)x)[tid] = ((const float4*)(memory + (size_t)b * DD))[tid];
  else           ((float4*)x)[tid] = ((const float4*)(read   + (size_t)b * DD))[tid - 128];
  __syncthreads();
  const int j = half * 256 + tid;
  float a = b_m1[j];
  #pragma unroll 8
  for (int k = 0; k < TD2; ++k) {
    a += x[k] * W_m1[(size_t)k * DD + j];
  }
  m1[(size_t)b * DD + j] = a;
}

// ---------------------------------------------------------------------------
// K6 (fused K4+final): reduce NCHUNK msa partials into LDS, then
// out[b,j] = (m1@W_m2 + msa@W_s + b_m2 + b_s)[j]*g + (1-g)*memory[b,j]
// grid: (2, B) — one j-half per block. block 256.
// ---------------------------------------------------------------------------
__global__ __launch_bounds__(256) void final_kernel(
    const float* __restrict__ m1, const float* __restrict__ partials,
    const float* __restrict__ W_m2, const float* __restrict__ b_m2,
    const float* __restrict__ W_s, const float* __restrict__ b_s,
    const float* __restrict__ gate, const float* __restrict__ memory,
    float* __restrict__ out) {
  const int half = blockIdx.x, b = blockIdx.y, tid = threadIdx.x;
  __shared__ float m1s[DD], msas[DD];
  // reduce partials: thread owns d = {2*tid, 2*tid+1}
  {
    float ax = 0.0f, ay = 0.0f;
    #pragma unroll
    for (int c = 0; c < NCHUNK; ++c) {
      const float2 p = *(const float2*)(partials +
          ((size_t)(b * NCHUNK + c)) * DD + tid * 2);
      ax += p.x; ay += p.y;
    }
    msas[tid * 2] = ax; msas[tid * 2 + 1] = ay;
    ((float2*)m1s)[tid] = ((const float2*)(m1 + (size_t)b * DD))[tid];
  }
  __syncthreads();
  const int j = half * 256 + tid;
  float a = b_m2[j] + b_s[j];
  #pragma unroll 4
  for (int k = 0; k < DD; ++k) {
    a += m1s[k] * W_m2[(size_t)k * DD + j] + msas[k] * W_s[(size_t)k * DD + j];
  }
  const float g = gate[b];
  const float me = memory[(size_t)b * DD + j];
  out[(size_t)b * DD + j] = a * g + (1.0f - g) * me;
}

// ---------------------------------------------------------------------------
extern "C" void kernel_launch(void* const* d_in, const int* in_sizes, int n_in,
                              void* d_out, int out_size, void* d_ws, size_t ws_size,
                              hipStream_t stream) {
  const float* memory = (const float*)d_in[0];
  const float* read   = (const float*)d_in[1];
  const float* control= (const float*)d_in[2];
  const float* past   = (const float*)d_in[3];
  const float* W_m1   = (const float*)d_in[4];
  const float* b_m1   = (const float*)d_in[5];
  const float* W_ca   = (const float*)d_in[6];
  const float* b_ca   = (const float*)d_in[7];
  const float* W_m2   = (const float*)d_in[8];
  const float* b_m2   = (const float*)d_in[9];
  const float* W_s    = (const float*)d_in[10];
  const float* b_s    = (const float*)d_in[11];
  const float* W_m3   = (const float*)d_in[12];
  const float* b_m3   = (const float*)d_in[13];
  float* out = (float*)d_out;

  // workspace layout (floats); all buffers fully written before read
  float* ws = (float*)d_ws;
  float* ca       = ws;                                   // B*T       = 262144
  float* partials = ca + (size_t)BB * TT;                 // B*16*D    = 1048576
  float* m1       = partials + (size_t)BB * NCHUNK * DD;  // B*D       = 65536
  float* gate     = m1 + (size_t)BB * DD;                 // B         = 128

  hipLaunchKernelGGL(ca_kernel, dim3(NCHUNK, BB), dim3(256), 0, stream,
                     past, control, W_ca, b_ca, ca);
  hipLaunchKernelGGL(softmax_gate_kernel, dim3(BB), dim3(256), 0, stream,
                     ca, control, W_m3, b_m3, gate);
  hipLaunchKernelGGL(msa_partial_kernel, dim3(NCHUNK, BB), dim3(256), 0, stream,
                     past, ca, partials);
  hipLaunchKernelGGL(m1_kernel, dim3(2, BB), dim3(256), 0, stream,
                     memory, read, W_m1, b_m1, m1);
  hipLaunchKernelGGL(final_kernel, dim3(2, BB), dim3(256), 0, stream,
                     m1, partials, W_m2, b_m2, W_s, b_s, gate, memory, out);
}